// Round 1
// baseline (29786.847 us; speedup 1.0000x reference)
//
#include <hip/hip_runtime.h>

#define NTHR 512
constexpr int BSZ = 32, TT = 128, NN = 128, MM = 64, NT = 192;

// ---- LDS layout (floats) ----
constexpr int VS_LD = 132;   // V   [128][132]  (padded: conflict-free float4 reads)
constexpr int U_LD  = 68;    // WB  [128][68]
constexpr int UW_LD = 36;    // WA slice [128][36] (aliases U region)
constexpr int KK_LD = 132;   // Qux/Y/K [64][132] (col 128 = qu/yq/k)
constexpr int QU_LD = 65;    // Quu/L [64][65]

constexpr int O_VS = 0;
constexpr int O_U  = O_VS + 128*VS_LD;   // 16896
constexpr int O_KK = O_U  + 128*U_LD;    // 25600
constexpr int O_QU = O_KK + 64*KK_LD;    // 34048
constexpr int O_SV = O_QU + 64*QU_LD;    // 38208  s = V c + v   [128]
constexpr int O_QH = O_SV + 128;         // 38336  qhat [192]
constexpr int O_VV = O_QH + 192;         // 38528  v [128]
constexpr int O_CS = O_VV + 128;         // 38656  c [128]
constexpr int O_DI = O_CS + 128;         // 38784  1/diag(L) [64]
constexpr int O_UU = O_DI + 64;          // 38848  u [64] (fwd)
constexpr int O_XN = O_UU + 64;          // 38912  x_next [128] (fwd)
constexpr int LDS_FLOATS = O_XN + 128;   // 39040 -> 156160 B
constexpr int LDS_BYTES = LDS_FLOATS * 4;

__device__ __forceinline__ void fma4(float4& acc, float a, const float4& b) {
    acc.x += a*b.x; acc.y += a*b.y; acc.z += a*b.z; acc.w += a*b.w;
}
__device__ __forceinline__ void fms4(float4& acc, float a, const float4& b) {
    acc.x -= a*b.x; acc.y -= a*b.y; acc.z -= a*b.z; acc.w -= a*b.w;
}

extern "C" __global__ __launch_bounds__(NTHR)
void lqr_kernel(const float* __restrict__ Ag, const float* __restrict__ Bg,
                const float* __restrict__ cg, const float* __restrict__ Qg,
                const float* __restrict__ pg, const float* __restrict__ x0g,
                float* __restrict__ tau, float* __restrict__ Kall,
                float* __restrict__ kall, float* __restrict__ Qxxg)
{
    extern __shared__ __align__(16) float sm[];
    const int b   = blockIdx.x;
    const int tid = threadIdx.x;

    float* Vs = sm + O_VS;
    float* U  = sm + O_U;
    float* KK = sm + O_KK;
    float* Qu = sm + O_QU;
    float* sv = sm + O_SV;
    float* qh = sm + O_QH;
    float* vv = sm + O_VV;
    float* cs = sm + O_CS;
    float* di = sm + O_DI;
    float* uu = sm + O_UU;
    float* xn = sm + O_XN;

    float* Qxg = Qxxg + (size_t)b * (NN*NN);
    const int bt0 = b * TT;

    // ---- init V = 0, v = 0 ----
    for (int i = tid; i < 128*VS_LD; i += NTHR) Vs[i] = 0.f;
    if (tid < 128) vv[tid] = 0.f;
    __syncthreads();

    // ======================= BACKWARD RICCATI SCAN =======================
    for (int t = TT - 1; t >= 0; --t) {
        const int bt = bt0 + t;
        const float* Ab = Ag + (size_t)bt * (NN*NN);
        const float* Bb = Bg + (size_t)bt * (NN*MM);
        const float* Qb = Qg + (size_t)bt * (NT*NT);
        const float* pb = pg + (size_t)bt * NT;
        const float* cb = cg + (size_t)bt * NN;

        // ---- load c ----
        if (tid < 128) cs[tid] = cb[tid];
        __syncthreads();

        // ---- s = V c + v ----
        if (tid < 128) {
            float acc = vv[tid];
            const float4* vr = (const float4*)(Vs + tid*VS_LD);
            const float4* c4 = (const float4*)cs;
            #pragma unroll 8
            for (int j = 0; j < 32; ++j) {
                float4 a = vr[j], c = c4[j];
                acc += a.x*c.x + a.y*c.y + a.z*c.z + a.w*c.w;
            }
            sv[tid] = acc;
        }
        __syncthreads();

        // ---- qhat = p + F^T s   (F = [A | B]) ----
        if (tid < 192) {
            float acc = pb[tid];
            if (tid < 128) {
                #pragma unroll 8
                for (int k = 0; k < 128; ++k) acc += Ab[k*NN + tid] * sv[k];
            } else {
                int m = tid - 128;
                #pragma unroll 8
                for (int k = 0; k < 128; ++k) acc += Bb[k*MM + m] * sv[k];
            }
            qh[tid] = acc;
        }

        // ---- WB = V * B  -> U[128][68] ----
        {
            int tr = tid >> 4, tc = tid & 15;   // 32 x 16
            int r0 = tr*4, c0 = tc*4;
            float4 acc[4] = {{0,0,0,0},{0,0,0,0},{0,0,0,0},{0,0,0,0}};
            #pragma unroll 4
            for (int k = 0; k < 128; ++k) {
                float4 av = *(const float4*)(Vs + k*VS_LD + r0);   // V[r0..r0+3][k]
                float4 bv = *(const float4*)(Bb + k*MM + c0);
                fma4(acc[0], av.x, bv); fma4(acc[1], av.y, bv);
                fma4(acc[2], av.z, bv); fma4(acc[3], av.w, bv);
            }
            #pragma unroll
            for (int r = 0; r < 4; ++r)
                *(float4*)(U + (r0+r)*U_LD + c0) = acc[r];
        }
        __syncthreads();

        // ---- Quu = Q0uu + WB^T B -> Qu[64][65] ----
        {
            int tr = tid >> 5, tc = tid & 31;   // 16 x 32
            int m0 = tr*4, n0 = tc*2;
            float acc[4][2];
            #pragma unroll
            for (int r = 0; r < 4; ++r) {
                acc[r][0] = Qb[(128+m0+r)*NT + 128 + n0];
                acc[r][1] = Qb[(128+m0+r)*NT + 128 + n0 + 1];
            }
            #pragma unroll 4
            for (int i = 0; i < 128; ++i) {
                float4 av = *(const float4*)(U + i*U_LD + m0);
                float2 bv = *(const float2*)(Bb + i*MM + n0);
                acc[0][0] += av.x*bv.x; acc[0][1] += av.x*bv.y;
                acc[1][0] += av.y*bv.x; acc[1][1] += av.y*bv.y;
                acc[2][0] += av.z*bv.x; acc[2][1] += av.z*bv.y;
                acc[3][0] += av.w*bv.x; acc[3][1] += av.w*bv.y;
            }
            #pragma unroll
            for (int r = 0; r < 4; ++r) {
                Qu[(m0+r)*QU_LD + n0]     = acc[r][0];
                Qu[(m0+r)*QU_LD + n0 + 1] = acc[r][1];
            }
        }

        // ---- Qux = Q0ux + WB^T A -> KK[64][132]; col 128 = qu ----
        {
            int tr = tid >> 5, tc = tid & 31;   // 16 x 32
            int m0 = tr*4, j0 = tc*4;
            float4 acc[4];
            #pragma unroll
            for (int r = 0; r < 4; ++r)
                acc[r] = *(const float4*)(Qb + (128+m0+r)*NT + j0);
            #pragma unroll 4
            for (int i = 0; i < 128; ++i) {
                float4 av = *(const float4*)(U + i*U_LD + m0);
                float4 bv = *(const float4*)(Ab + i*NN + j0);
                fma4(acc[0], av.x, bv); fma4(acc[1], av.y, bv);
                fma4(acc[2], av.z, bv); fma4(acc[3], av.w, bv);
            }
            #pragma unroll
            for (int r = 0; r < 4; ++r)
                *(float4*)(KK + (m0+r)*KK_LD + j0) = acc[r];
        }
        if (tid < 64) KK[tid*KK_LD + 128] = qh[128 + tid];
        __syncthreads();

        // ---- Qxx = Q0xx + A^T (V A), in 32-col slices -> ws ----
        for (int J = 0; J < 128; J += 32) {
            {   // WA_J = V * A[:,J:J+32] -> U[128][36]
                int tr = tid >> 3, tc = tid & 7;   // 64 x 8
                int r0 = tr*2, c0 = tc*4;
                float4 a0 = {0,0,0,0}, a1 = {0,0,0,0};
                #pragma unroll 4
                for (int k = 0; k < 128; ++k) {
                    float2 av = *(const float2*)(Vs + k*VS_LD + r0);
                    float4 bv = *(const float4*)(Ab + k*NN + J + c0);
                    fma4(a0, av.x, bv); fma4(a1, av.y, bv);
                }
                *(float4*)(U + (r0+0)*UW_LD + c0) = a0;
                *(float4*)(U + (r0+1)*UW_LD + c0) = a1;
            }
            __syncthreads();
            {   // Qxx[:,J..] = Q0 + A^T WA_J -> Qxg
                int tr = tid >> 4, tc = tid & 15;  // 32 x 16
                int i0 = tr*4, jj0 = tc*2;
                float acc[4][2];
                #pragma unroll
                for (int r = 0; r < 4; ++r) {
                    acc[r][0] = Qb[(i0+r)*NT + J + jj0];
                    acc[r][1] = Qb[(i0+r)*NT + J + jj0 + 1];
                }
                #pragma unroll 4
                for (int k = 0; k < 128; ++k) {
                    float4 av = *(const float4*)(Ab + k*NN + i0);
                    float2 bv = *(const float2*)(U + k*UW_LD + jj0);
                    acc[0][0] += av.x*bv.x; acc[0][1] += av.x*bv.y;
                    acc[1][0] += av.y*bv.x; acc[1][1] += av.y*bv.y;
                    acc[2][0] += av.z*bv.x; acc[2][1] += av.z*bv.y;
                    acc[3][0] += av.w*bv.x; acc[3][1] += av.w*bv.y;
                }
                #pragma unroll
                for (int r = 0; r < 4; ++r) {
                    float2 st = {acc[r][0], acc[r][1]};
                    *(float2*)(Qxg + (i0+r)*NN + J + jj0) = st;
                }
            }
            __syncthreads();
        }

        // ---- Cholesky Quu = L L^T (lower, in place), blocked 16 ----
        for (int jb = 0; jb < 64; jb += 16) {
            if (tid < 64) {     // wave 0: factor diagonal block (lockstep)
                volatile float* Qv = Qu;
                for (int j = 0; j < 16; ++j) {
                    int col = jb + j;
                    float djj = Qv[col*QU_LD + col];
                    float sdj = sqrtf(djj);
                    float ri  = 1.0f / sdj;
                    if (tid == j) { Qv[col*QU_LD + col] = sdj; di[col] = ri; }
                    if (tid > j && tid < 16) {
                        int row = jb + tid;
                        float lij = Qv[row*QU_LD + col] * ri;
                        Qv[row*QU_LD + col] = lij;
                        for (int kk = j+1; kk <= tid; ++kk)
                            Qv[row*QU_LD + jb + kk] -= lij * Qv[(jb+kk)*QU_LD + col];
                    }
                }
            }
            __syncthreads();
            {   // panel: rows below solve vs diag block
                int r = jb + 16 + tid;
                if (r < 64) {
                    float y[16];
                    #pragma unroll
                    for (int j = 0; j < 16; ++j) y[j] = Qu[r*QU_LD + jb + j];
                    #pragma unroll
                    for (int j = 0; j < 16; ++j) {
                        float acc = y[j];
                        for (int kk = 0; kk < j; ++kk)
                            acc -= Qu[(jb+j)*QU_LD + jb + kk] * y[kk];
                        y[j] = acc * di[jb + j];
                    }
                    #pragma unroll
                    for (int j = 0; j < 16; ++j) Qu[r*QU_LD + jb + j] = y[j];
                }
            }
            __syncthreads();
            {   // trailing update (lower triangle only)
                int nr = 64 - (jb + 16);
                int ro = tid >> 3, cc = tid & 7;
                int i = jb + 16 + ro;
                if (ro < nr) {
                    float li[16];
                    #pragma unroll
                    for (int j = 0; j < 16; ++j) li[j] = Qu[i*QU_LD + jb + j];
                    for (int kk = jb + 16 + cc; kk <= i; kk += 8) {
                        float acc = Qu[i*QU_LD + kk];
                        #pragma unroll
                        for (int j = 0; j < 16; ++j)
                            acc -= li[j] * Qu[kk*QU_LD + jb + j];
                        Qu[i*QU_LD + kk] = acc;
                    }
                }
            }
            __syncthreads();
        }

        // ---- forward substitution: Y = L^{-1} [Qux | qu]  (in KK) ----
        for (int jb = 0; jb < 64; jb += 16) {
            for (int c = tid; c < 129; c += NTHR) {
                float y[16];
                #pragma unroll
                for (int j = 0; j < 16; ++j) y[j] = KK[(jb+j)*KK_LD + c];
                #pragma unroll
                for (int j = 0; j < 16; ++j) {
                    float acc = y[j];
                    for (int kk = 0; kk < j; ++kk)
                        acc -= Qu[(jb+j)*QU_LD + jb + kk] * y[kk];
                    y[j] = acc * di[jb+j];
                }
                #pragma unroll
                for (int j = 0; j < 16; ++j) KK[(jb+j)*KK_LD + c] = y[j];
            }
            __syncthreads();
            if (jb < 48) {
                int c = tid & 127, ro = tid >> 7;
                for (int i = jb + 16 + ro; i < 64; i += 4) {
                    float acc = KK[i*KK_LD + c];
                    #pragma unroll
                    for (int j = 0; j < 16; ++j)
                        acc -= Qu[i*QU_LD + jb + j] * KK[(jb+j)*KK_LD + c];
                    KK[i*KK_LD + c] = acc;
                }
                if (tid >= NTHR - 8) {
                    int ro2 = tid - (NTHR - 8);
                    for (int i = jb + 16 + ro2; i < 64; i += 8) {
                        float acc = KK[i*KK_LD + 128];
                        #pragma unroll
                        for (int j = 0; j < 16; ++j)
                            acc -= Qu[i*QU_LD + jb + j] * KK[(jb+j)*KK_LD + 128];
                        KK[i*KK_LD + 128] = acc;
                    }
                }
            }
            __syncthreads();
        }

        // ---- Vn = Qxx - Y^T Y -> Vs ; vn = qx - Y^T yq -> vv ----
        if (tid < 128) {
            float acc = qh[tid];
            #pragma unroll 8
            for (int m = 0; m < 64; ++m)
                acc -= KK[m*KK_LD + tid] * KK[m*KK_LD + 128];
            vv[tid] = acc;
        }
        {
            int tc = tid & 31, tq = tid >> 5;   // 16 x 32
            #pragma unroll
            for (int half = 0; half < 2; ++half) {
                int i0 = half*64 + tq*4, j0 = tc*4;
                float4 acc[4];
                #pragma unroll
                for (int r = 0; r < 4; ++r)
                    acc[r] = *(const float4*)(Qxg + (i0+r)*NN + j0);
                #pragma unroll 4
                for (int m = 0; m < 64; ++m) {
                    float4 av = *(const float4*)(KK + m*KK_LD + i0);
                    float4 bv = *(const float4*)(KK + m*KK_LD + j0);
                    fms4(acc[0], av.x, bv); fms4(acc[1], av.y, bv);
                    fms4(acc[2], av.z, bv); fms4(acc[3], av.w, bv);
                }
                #pragma unroll
                for (int r = 0; r < 4; ++r)
                    *(float4*)(Vs + (i0+r)*VS_LD + j0) = acc[r];
            }
        }
        __syncthreads();

        // ---- back substitution: K' = L^{-T} Y  (K = -K') ----
        for (int jb = 48; jb >= 0; jb -= 16) {
            for (int c = tid; c < 129; c += NTHR) {
                float y[16];
                #pragma unroll
                for (int j = 0; j < 16; ++j) y[j] = KK[(jb+j)*KK_LD + c];
                #pragma unroll
                for (int j = 15; j >= 0; --j) {
                    float acc = y[j];
                    for (int kk = j+1; kk < 16; ++kk)
                        acc -= Qu[(jb+kk)*QU_LD + jb + j] * y[kk];
                    y[j] = acc * di[jb+j];
                }
                #pragma unroll
                for (int j = 0; j < 16; ++j) KK[(jb+j)*KK_LD + c] = y[j];
            }
            __syncthreads();
            if (jb > 0) {
                int c = tid & 127, ro = tid >> 7;
                for (int i = ro; i < jb; i += 4) {
                    float acc = KK[i*KK_LD + c];
                    #pragma unroll
                    for (int j = 0; j < 16; ++j)
                        acc -= Qu[(jb+j)*QU_LD + i] * KK[(jb+j)*KK_LD + c];
                    KK[i*KK_LD + c] = acc;
                }
                if (tid >= NTHR - 8) {
                    int ro2 = tid - (NTHR - 8);
                    for (int i = ro2; i < jb; i += 8) {
                        float acc = KK[i*KK_LD + 128];
                        #pragma unroll
                        for (int j = 0; j < 16; ++j)
                            acc -= Qu[(jb+j)*QU_LD + i] * KK[(jb+j)*KK_LD + 128];
                        KK[i*KK_LD + 128] = acc;
                    }
                }
            }
            __syncthreads();
        }

        // ---- write K = -K', k = -k' ----
        {
            float* Kb = Kall + (size_t)bt * (MM*NN);
            for (int idx = tid; idx < MM*NN; idx += NTHR) {
                int m = idx >> 7, j = idx & 127;
                Kb[idx] = -KK[m*KK_LD + j];
            }
            if (tid < 64) kall[(size_t)bt*MM + tid] = -KK[tid*KK_LD + 128];
        }
        __syncthreads();
    }

    // ======================= FORWARD ROLLOUT =======================
    if (tid < 128) sv[tid] = x0g[b*NN + tid];
    __syncthreads();
    const int wv = tid >> 6, lane = tid & 63;
    for (int t = 0; t < TT; ++t) {
        const int bt = bt0 + t;
        const float* Kb = Kall + (size_t)bt * (MM*NN);
        const float* kb = kall + (size_t)bt * MM;
        const float* Ab = Ag + (size_t)bt * (NN*NN);
        const float* Bb = Bg + (size_t)bt * (NN*MM);
        const float* cb = cg + (size_t)bt * NN;

        // u = K x + k  (one row per wave-pass, shuffle reduce)
        #pragma unroll
        for (int r = 0; r < 8; ++r) {
            int m = wv*8 + r;
            float part = Kb[m*NN + lane] * sv[lane]
                       + Kb[m*NN + 64 + lane] * sv[64 + lane];
            #pragma unroll
            for (int off = 32; off > 0; off >>= 1) part += __shfl_down(part, off, 64);
            if (lane == 0) uu[m] = part + kb[m];
        }
        __syncthreads();

        // tau[b,t] = [x ; u]
        float* tb = tau + (size_t)bt * NT;
        if (tid < 192) tb[tid] = (tid < 128) ? sv[tid] : uu[tid - 128];

        // x' = A x + B u + c
        #pragma unroll
        for (int r = 0; r < 16; ++r) {
            int i = wv*16 + r;
            float part = Ab[i*NN + lane] * sv[lane]
                       + Ab[i*NN + 64 + lane] * sv[64 + lane]
                       + Bb[i*MM + lane] * uu[lane];
            #pragma unroll
            for (int off = 32; off > 0; off >>= 1) part += __shfl_down(part, off, 64);
            if (lane == 0) xn[i] = part + cb[i];
        }
        __syncthreads();
        if (tid < 128) sv[tid] = xn[tid];
        __syncthreads();
    }
}

extern "C" void kernel_launch(void* const* d_in, const int* in_sizes, int n_in,
                              void* d_out, int out_size, void* d_ws, size_t ws_size,
                              hipStream_t stream) {
    (void)in_sizes; (void)n_in; (void)out_size; (void)ws_size;
    const float* A  = (const float*)d_in[0];
    const float* Bm = (const float*)d_in[1];
    const float* c1 = (const float*)d_in[2];
    const float* Q  = (const float*)d_in[3];
    const float* p  = (const float*)d_in[4];
    const float* x0 = (const float*)d_in[5];
    float* tau = (float*)d_out;

    float* ws   = (float*)d_ws;
    float* Kall = ws;                                      // 32*128*64*128
    float* kall = Kall + (size_t)BSZ*TT*MM*NN;             // 32*128*64
    float* Qxxg = kall + (size_t)BSZ*TT*MM;                // 32*128*128

    // allow >64KB dynamic LDS (ignore error if not needed on this ROCm)
    (void)hipFuncSetAttribute((const void*)lqr_kernel,
                              hipFuncAttributeMaxDynamicSharedMemorySize, LDS_BYTES);

    lqr_kernel<<<dim3(BSZ), dim3(NTHR), LDS_BYTES, stream>>>(
        A, Bm, c1, Q, p, x0, tau, Kall, kall, Qxxg);
}